// Round 3
// baseline (475.003 us; speedup 1.0000x reference)
//
#include <hip/hip_runtime.h>
#include <stdint.h>

typedef unsigned short u16;
typedef __attribute__((ext_vector_type(4))) float f32x4;
typedef __attribute__((ext_vector_type(16))) float f32x16;
typedef __attribute__((ext_vector_type(8))) short s16x8;
typedef __attribute__((ext_vector_type(8))) __bf16 bf16x8;
typedef __attribute__((ext_vector_type(8))) unsigned short u16x8;
typedef __attribute__((ext_vector_type(4))) unsigned short u16x4;

__device__ __forceinline__ f32x4 mfma16(s16x8 a, s16x8 b, f32x4 c) {
  return __builtin_amdgcn_mfma_f32_16x16x32_bf16(
      __builtin_bit_cast(bf16x8, a), __builtin_bit_cast(bf16x8, b), c, 0, 0, 0);
}
__device__ __forceinline__ f32x16 mfma32(s16x8 a, s16x8 b, f32x16 c) {
  return __builtin_amdgcn_mfma_f32_32x32x16_bf16(
      __builtin_bit_cast(bf16x8, a), __builtin_bit_cast(bf16x8, b), c, 0, 0, 0);
}

__device__ __forceinline__ void gl_lds16(const u16* g, u16* l) {
  __builtin_amdgcn_global_load_lds(
      (const __attribute__((address_space(1))) void*)g,
      (__attribute__((address_space(3))) void*)l, 16, 0, 0);
}

__device__ __forceinline__ u16 bf16rne(float f) {
  uint32_t u = __builtin_bit_cast(uint32_t, f);
  u += 0x7fffu + ((u >> 16) & 1u);
  return (u16)(u >> 16);
}

// ---------------- cast x (f32 -> bf16) ----------------
__global__ void cast_x_kernel(const float* __restrict__ x, u16* __restrict__ xb) {
  size_t i = ((size_t)blockIdx.x * 256 + threadIdx.x) * 8;
  f32x4 a = *(const f32x4*)(x + i);
  f32x4 b = *(const f32x4*)(x + i + 4);
  u16x8 o;
#pragma unroll
  for (int j = 0; j < 4; ++j) { o[j] = bf16rne(a[j]); o[4 + j] = bf16rne(b[j]); }
  *(u16x8*)(xb + i) = o;
}

// ------- cast W -> Wt[768][2048] bf16 (WQ rows pre-scaled by scale*log2e) -------
__global__ void cast_w_kernel(const float* __restrict__ WQ, const float* __restrict__ WK,
                              const float* __restrict__ WV, u16* __restrict__ Wt, float qscale) {
  int i = blockIdx.x * 256 + threadIdx.x;  // 768*2048 threads
  int r = i >> 11, k = i & 2047;
  int sel = r >> 8, c = r & 255;
  const float* W = (sel == 0) ? WQ : (sel == 1) ? WK : WV;
  float v = W[(size_t)k * 256 + c];
  if (sel == 0) v *= qscale;
  Wt[i] = bf16rne(v);
}

// ---------------- QKV projection GEMM: [16384,2048] x [2048,768] ----------------
// XCD-swizzled so the 6 n-blocks sharing an m-tile are co-resident on one XCD
// (x fetched from HBM once, not 6x). V is written transposed: Vt[b][col][s].
__global__ __launch_bounds__(256) void proj_gemm(const u16* __restrict__ xb, const u16* __restrict__ Wt,
                                                 u16* __restrict__ Qb, u16* __restrict__ Kb,
                                                 u16* __restrict__ Vt) {
  const int bid = blockIdx.x;             // 768 blocks, all co-resident (3/CU)
  const int xcd = bid & 7, j = bid >> 3;  // j in 0..95
  const int m0 = (xcd * 16 + (j / 6)) * 128;
  const int n0 = (j % 6) * 128;
  const int tid = threadIdx.x, lane = tid & 63, w = tid >> 6;
  const int ln = lane & 15, quad = lane >> 4;
  const int wm = w & 1, wn = w >> 1;
  __shared__ __align__(16) u16 As[128 * 32];
  __shared__ __align__(16) u16 Bs[128 * 32];
  f32x4 acc[4][4];
#pragma unroll
  for (int i = 0; i < 4; ++i)
#pragma unroll
    for (int jj = 0; jj < 4; ++jj) acc[i][jj] = f32x4{0.f, 0.f, 0.f, 0.f};

  for (int kk = 0; kk < 2048; kk += 32) {
    __syncthreads();
#pragma unroll
    for (int i = 0; i < 2; ++i) {
      int p = tid + i * 256;
      int row = p >> 2, cg = (p & 3) ^ (row & 3);
      gl_lds16(xb + (size_t)(m0 + row) * 2048 + kk + cg * 8, As + (size_t)(p - lane) * 8);
      gl_lds16(Wt + (size_t)(n0 + row) * 2048 + kk + cg * 8, Bs + (size_t)(p - lane) * 8);
    }
    __syncthreads();
    s16x8 a[4];
#pragma unroll
    for (int mt = 0; mt < 4; ++mt) {
      int r = wm * 64 + mt * 16 + ln;
      a[mt] = *(const s16x8*)(As + r * 32 + ((quad ^ (r & 3)) * 8));
    }
#pragma unroll
    for (int nt = 0; nt < 4; ++nt) {
      int r = wn * 64 + nt * 16 + ln;
      s16x8 bf = *(const s16x8*)(Bs + r * 32 + ((quad ^ (r & 3)) * 8));
#pragma unroll
      for (int mt = 0; mt < 4; ++mt) acc[mt][nt] = mfma16(a[mt], bf, acc[mt][nt]);
    }
  }
#pragma unroll
  for (int mt = 0; mt < 4; ++mt)
#pragma unroll
    for (int nt = 0; nt < 4; ++nt) {
      int row0 = m0 + wm * 64 + mt * 16 + quad * 4;
      int col = n0 + wn * 64 + nt * 16 + ln;
      int sel = col >> 8, c = col & 255;
      u16x4 vv;
#pragma unroll
      for (int jj = 0; jj < 4; ++jj) vv[jj] = bf16rne(acc[mt][nt][jj]);
      if (sel == 2) {
        int b = row0 >> 12, s = row0 & 4095;
        *(u16x4*)(Vt + (size_t)b * 1048576 + (size_t)c * 4096 + s) = vv;
      } else {
        u16* dst = (sel == 0) ? Qb : Kb;
#pragma unroll
        for (int jj = 0; jj < 4; ++jj) dst[(size_t)(row0 + jj) * 256 + c] = vv[jj];
      }
    }
}

// ---------------- lambda scalar ----------------
__global__ void lam_kernel(const float* __restrict__ lq1, const float* __restrict__ lq2,
                           const float* __restrict__ lk1, const float* __restrict__ lk2,
                           float* __restrict__ lamp) {
  int t = threadIdx.x;  // 64 threads
  float d1 = lq1[t] * lk1[t] + lq1[t + 64] * lk1[t + 64];
  float d2 = lq2[t] * lk2[t] + lq2[t + 64] * lk2[t + 64];
#pragma unroll
  for (int off = 32; off; off >>= 1) {
    d1 += __shfl_xor(d1, off);
    d2 += __shfl_xor(d2, off);
  }
  if (t == 0) *lamp = expf(d1) + expf(d2) + (0.8f - 0.6f * expf(-3.6f));
}

// --------- fused-map flash attention (no-max softmax), 32x32x16 MFMA ---------
// grid: (qt 64, half 2, b 4) = 512 blocks = exactly 2/CU at 64KB LDS.
// Per block: q-tile 64 (both maps), key loop 64/iter over this half's 2048 keys.
// Wave w: QK for map (w&1), q row-tile (w>>1); PV for P-rows of map (w&1),
// v-cols (w>>1)*128..+128. Writes unnormalized Op[mh][row][256], lp[mh][row],
// mh = map*2 + half.
__global__ __launch_bounds__(256, 2) void attn_kernel(const u16* __restrict__ Qb,
                                                      const u16* __restrict__ Kb,
                                                      const u16* __restrict__ Vt,
                                                      float* __restrict__ Op,
                                                      float* __restrict__ lp) {
  const int qt = blockIdx.x, half = blockIdx.y, b = blockIdx.z;
  const int tid = threadIdx.x, lane = tid & 63, w = tid >> 6;
  const int l5 = lane & 31, lh = lane >> 5;
  const int mapsel = w & 1, rt = w >> 1;

  __shared__ __align__(16) u16 Ks[64 * 256];  // 32KB: K[64 keys][256 d]; Ps aliases
  __shared__ __align__(16) u16 Vs[256 * 64];  // 32KB: V^T[256 vcol][64 keys]
  u16* Ps = Ks;                               // P[128 q'][72 pitch]

  // Q preload: A-frags for S_map[mapsel], rows rt*32 + l5, 8 k-steps of 16
  s16x8 aq[8];
  {
    const u16* qp = Qb + ((size_t)(b * 4096 + qt * 64 + rt * 32 + l5)) * 256 +
                    mapsel * 128 + lh * 8;
#pragma unroll
    for (int st = 0; st < 8; ++st) aq[st] = *(const s16x8*)(qp + st * 16);
  }

  f32x16 O[2][4];
#pragma unroll
  for (int i = 0; i < 2; ++i)
#pragma unroll
    for (int jj = 0; jj < 4; ++jj)
#pragma unroll
      for (int r = 0; r < 16; ++r) O[i][jj][r] = 0.f;
  float l_run[16];
#pragma unroll
  for (int r = 0; r < 16; ++r) l_run[r] = 0.f;

  const u16* Kg0 = Kb + ((size_t)b * 4096) * 256;
  const u16* Vg0 = Vt + (size_t)b * 1048576;
  const int kb0 = half * 2048;

  for (int kb = kb0; kb < kb0 + 2048; kb += 64) {
    __syncthreads();  // prior PV reads of Ps(=Ks)/Vs complete
    // stage K[64 keys][256 d] (32KB, chunk-swizzled within row)
#pragma unroll
    for (int i = 0; i < 8; ++i) {
      int p = tid + i * 256;
      int row = p >> 5, c = p & 31;
      int cg = (c & 16) | ((c ^ row) & 15);
      gl_lds16(Kg0 + (size_t)(kb + row) * 256 + cg * 8, Ks + (size_t)(p - lane) * 8);
    }
    // stage V^T[256 vcol][64 keys] (32KB, chunk-swizzled)
#pragma unroll
    for (int i = 0; i < 8; ++i) {
      int p = tid + i * 256;
      int row = p >> 3, c = p & 7;
      int cg = c ^ (row & 7);
      gl_lds16(Vg0 + (size_t)row * 4096 + kb + cg * 8, Vs + (size_t)(p - lane) * 8);
    }
    __syncthreads();

    // QK^T: wave computes S[32 q][64 keys] for its map as two 32x32 tiles
    f32x16 S0, S1;
#pragma unroll
    for (int r = 0; r < 16; ++r) { S0[r] = 0.f; S1[r] = 0.f; }
#pragma unroll
    for (int st = 0; st < 8; ++st) {
      int c = mapsel * 16 + st * 2 + lh;
      int ph0 = (c & 16) | ((c ^ l5) & 15);
      s16x8 b0 = *(const s16x8*)(Ks + l5 * 256 + ph0 * 8);
      s16x8 b1 = *(const s16x8*)(Ks + (32 + l5) * 256 + ph0 * 8);
      S0 = mfma32(aq[st], b0, S0);
      S1 = mfma32(aq[st], b1, S1);
    }

    // p = exp2(s); accumulate per-lane l (all 64 keys of this wave's rows)
    __syncthreads();  // all K-frag reads done before P overwrites Ks
    {
      int qbase = mapsel * 64 + rt * 32 + 4 * lh;
#pragma unroll
      for (int r = 0; r < 16; ++r) {
        float p0 = exp2f(S0[r]);
        float p1 = exp2f(S1[r]);
        l_run[r] += p0 + p1;
        int qrow = qbase + (r & 3) + 8 * (r >> 2);
        Ps[qrow * 72 + l5] = bf16rne(p0);
        Ps[qrow * 72 + 32 + l5] = bf16rne(p1);
      }
    }
    __syncthreads();

    // PV: wave computes O[map (w&1) P-rows 64][v-cols (w>>1)*128..+128]
#pragma unroll
    for (int ks = 0; ks < 4; ++ks) {
      s16x8 ap0 = *(const s16x8*)(Ps + (mapsel * 64 + l5) * 72 + ks * 16 + lh * 8);
      s16x8 ap1 = *(const s16x8*)(Ps + (mapsel * 64 + 32 + l5) * 72 + ks * 16 + lh * 8);
      int c = ks * 2 + lh;
#pragma unroll
      for (int ct = 0; ct < 4; ++ct) {
        int n = (w >> 1) * 128 + ct * 32 + l5;
        s16x8 bv = *(const s16x8*)(Vs + n * 64 + ((c ^ (n & 7)) * 8));
        O[0][ct] = mfma32(ap0, bv, O[0][ct]);
        O[1][ct] = mfma32(ap1, bv, O[1][ct]);
      }
    }
  }

  // epilogue: reduce l across the 32 lanes of each half (q differs by lh)
#pragma unroll
  for (int off = 16; off; off >>= 1)
#pragma unroll
    for (int r = 0; r < 16; ++r) l_run[r] += __shfl_xor(l_run[r], off);

  const int mh = mapsel * 2 + half;
  const size_t MS = (size_t)16384 * 256;
  float* Og = Op + (size_t)mh * MS + (size_t)b * 4096 * 256;
  float* lg = lp + (size_t)mh * 16384 + (size_t)b * 4096;
  if (l5 == 0) {
#pragma unroll
    for (int r = 0; r < 16; ++r) {
      int qg = qt * 64 + rt * 32 + 4 * lh + (r & 3) + 8 * (r >> 2);
      lg[qg] = l_run[r];
    }
  }
#pragma unroll
  for (int rt2 = 0; rt2 < 2; ++rt2)
#pragma unroll
    for (int ct = 0; ct < 4; ++ct)
#pragma unroll
      for (int r = 0; r < 16; ++r) {
        int qg = qt * 64 + rt2 * 32 + (r & 3) + 8 * (r >> 2) + 4 * lh;
        int col = (w >> 1) * 128 + ct * 32 + l5;
        Og[(size_t)qg * 256 + col] = O[rt2][ct][r];
      }
}

// -------- combine: out = (O00+O01)/(l00+l01) - lam*(O10+O11)/(l10+l11) --------
__global__ void combine_kernel(const float* __restrict__ Op, const float* __restrict__ lp,
                               const float* __restrict__ lamp, float* __restrict__ out) {
  size_t i = ((size_t)blockIdx.x * 256 + threadIdx.x) * 4;
  size_t row = i >> 8;
  const size_t MS = (size_t)16384 * 256;
  float lam = *lamp;
  float r1 = 1.f / (lp[row] + lp[16384 + row]);
  float r2 = 1.f / (lp[2 * 16384 + row] + lp[3 * 16384 + row]);
  f32x4 a0 = *(const f32x4*)(Op + i);
  f32x4 a1 = *(const f32x4*)(Op + MS + i);
  f32x4 b0 = *(const f32x4*)(Op + 2 * MS + i);
  f32x4 b1 = *(const f32x4*)(Op + 3 * MS + i);
  f32x4 r;
#pragma unroll
  for (int j = 0; j < 4; ++j) r[j] = (a0[j] + a1[j]) * r1 - lam * (b0[j] + b1[j]) * r2;
  *(f32x4*)(out + i) = r;
}

extern "C" void kernel_launch(void* const* d_in, const int* in_sizes, int n_in,
                              void* d_out, int out_size, void* d_ws, size_t ws_size,
                              hipStream_t stream) {
  (void)in_sizes; (void)n_in; (void)out_size; (void)ws_size;
  const float* x   = (const float*)d_in[0];
  const float* WQ  = (const float*)d_in[1];
  const float* WK  = (const float*)d_in[2];
  const float* WV  = (const float*)d_in[3];
  const float* lq1 = (const float*)d_in[4];
  const float* lq2 = (const float*)d_in[5];
  const float* lk1 = (const float*)d_in[6];
  const float* lk2 = (const float*)d_in[7];
  float* out = (float*)d_out;

  char* ws = (char*)d_ws;
  u16* xb = (u16*)ws;   ws += (size_t)16384 * 2048 * 2;
  u16* Wt = (u16*)ws;   ws += (size_t)768 * 2048 * 2;
  u16* Qb = (u16*)ws;   ws += (size_t)16384 * 256 * 2;
  u16* Kb = (u16*)ws;   ws += (size_t)16384 * 256 * 2;
  u16* Vt = (u16*)ws;   ws += (size_t)16384 * 256 * 2;  // [b][col 256][s 4096]
  float* Op = (float*)ws; ws += (size_t)4 * 16384 * 256 * 4;  // [map*2+half][16384][256]
  float* lp = (float*)ws; ws += (size_t)4 * 16384 * 4;        // [map*2+half][16384]
  float* lamp = (float*)ws;

  const float qscale = 0.0883883476f * 1.44269504f;  // HEAD_DIM^-0.5 * log2(e)

  hipLaunchKernelGGL(cast_x_kernel, dim3(16384), dim3(256), 0, stream, x, xb);
  hipLaunchKernelGGL(cast_w_kernel, dim3(6144), dim3(256), 0, stream, WQ, WK, WV, Wt, qscale);
  hipLaunchKernelGGL(proj_gemm, dim3(768), dim3(256), 0, stream, xb, Wt, Qb, Kb, Vt);
  hipLaunchKernelGGL(lam_kernel, dim3(1), dim3(64), 0, stream, lq1, lq2, lk1, lk2, lamp);
  hipLaunchKernelGGL(attn_kernel, dim3(64, 2, 4), dim3(256), 0, stream, Qb, Kb, Vt, Op, lp);
  hipLaunchKernelGGL(combine_kernel, dim3(4096), dim3(256), 0, stream, Op, lp, lamp, out);
}

// Round 4
// 430.284 us; speedup vs baseline: 1.1039x; 1.1039x over previous
//
#include <hip/hip_runtime.h>
#include <stdint.h>

typedef unsigned short u16;
typedef __attribute__((ext_vector_type(4))) float f32x4;
typedef __attribute__((ext_vector_type(16))) float f32x16;
typedef __attribute__((ext_vector_type(8))) short s16x8;
typedef __attribute__((ext_vector_type(8))) __bf16 bf16x8;
typedef __attribute__((ext_vector_type(8))) unsigned short u16x8;
typedef __attribute__((ext_vector_type(4))) unsigned short u16x4;
typedef __attribute__((ext_vector_type(4))) uint32_t u32x4;

__device__ __forceinline__ f32x4 mfma16(s16x8 a, s16x8 b, f32x4 c) {
  return __builtin_amdgcn_mfma_f32_16x16x32_bf16(
      __builtin_bit_cast(bf16x8, a), __builtin_bit_cast(bf16x8, b), c, 0, 0, 0);
}
__device__ __forceinline__ f32x16 mfma32(s16x8 a, s16x8 b, f32x16 c) {
  return __builtin_amdgcn_mfma_f32_32x32x16_bf16(
      __builtin_bit_cast(bf16x8, a), __builtin_bit_cast(bf16x8, b), c, 0, 0, 0);
}

__device__ __forceinline__ void gl_lds16(const u16* g, u16* l) {
  __builtin_amdgcn_global_load_lds(
      (const __attribute__((address_space(1))) void*)g,
      (__attribute__((address_space(3))) void*)l, 16, 0, 0);
}

__device__ __forceinline__ u16 bf16rne(float f) {
  uint32_t u = __builtin_bit_cast(uint32_t, f);
  u += 0x7fffu + ((u >> 16) & 1u);
  return (u16)(u >> 16);
}

// ---------------- cast x (f32 -> bf16) ----------------
__global__ void cast_x_kernel(const float* __restrict__ x, u16* __restrict__ xb) {
  size_t i = ((size_t)blockIdx.x * 256 + threadIdx.x) * 8;
  f32x4 a = *(const f32x4*)(x + i);
  f32x4 b = *(const f32x4*)(x + i + 4);
  u16x8 o;
#pragma unroll
  for (int j = 0; j < 4; ++j) { o[j] = bf16rne(a[j]); o[4 + j] = bf16rne(b[j]); }
  *(u16x8*)(xb + i) = o;
}

// ------- cast W -> Wt[768][2048] bf16 (WQ rows pre-scaled by scale*log2e) -------
__global__ void cast_w_kernel(const float* __restrict__ WQ, const float* __restrict__ WK,
                              const float* __restrict__ WV, u16* __restrict__ Wt, float qscale) {
  int i = blockIdx.x * 256 + threadIdx.x;  // 768*2048 threads
  int r = i >> 11, k = i & 2047;
  int sel = r >> 8, c = r & 255;
  const float* W = (sel == 0) ? WQ : (sel == 1) ? WK : WV;
  float v = W[(size_t)k * 256 + c];
  if (sel == 0) v *= qscale;
  Wt[i] = bf16rne(v);
}

// ---------------- QKV projection GEMM: [16384,2048] x [2048,768] ----------------
// XCD-swizzled; V written transposed: Vt[b][col][s].
__global__ __launch_bounds__(256) void proj_gemm(const u16* __restrict__ xb, const u16* __restrict__ Wt,
                                                 u16* __restrict__ Qb, u16* __restrict__ Kb,
                                                 u16* __restrict__ Vt) {
  const int bid = blockIdx.x;             // 768 blocks
  const int xcd = bid & 7, j = bid >> 3;  // j in 0..95
  const int m0 = (xcd * 16 + (j / 6)) * 128;
  const int n0 = (j % 6) * 128;
  const int tid = threadIdx.x, lane = tid & 63, w = tid >> 6;
  const int ln = lane & 15, quad = lane >> 4;
  const int wm = w & 1, wn = w >> 1;
  __shared__ __align__(16) u16 As[128 * 32];
  __shared__ __align__(16) u16 Bs[128 * 32];
  f32x4 acc[4][4];
#pragma unroll
  for (int i = 0; i < 4; ++i)
#pragma unroll
    for (int jj = 0; jj < 4; ++jj) acc[i][jj] = f32x4{0.f, 0.f, 0.f, 0.f};

  for (int kk = 0; kk < 2048; kk += 32) {
    __syncthreads();
#pragma unroll
    for (int i = 0; i < 2; ++i) {
      int p = tid + i * 256;
      int row = p >> 2, cg = (p & 3) ^ (row & 3);
      gl_lds16(xb + (size_t)(m0 + row) * 2048 + kk + cg * 8, As + (size_t)(p - lane) * 8);
      gl_lds16(Wt + (size_t)(n0 + row) * 2048 + kk + cg * 8, Bs + (size_t)(p - lane) * 8);
    }
    __syncthreads();
    s16x8 a[4];
#pragma unroll
    for (int mt = 0; mt < 4; ++mt) {
      int r = wm * 64 + mt * 16 + ln;
      a[mt] = *(const s16x8*)(As + r * 32 + ((quad ^ (r & 3)) * 8));
    }
#pragma unroll
    for (int nt = 0; nt < 4; ++nt) {
      int r = wn * 64 + nt * 16 + ln;
      s16x8 bf = *(const s16x8*)(Bs + r * 32 + ((quad ^ (r & 3)) * 8));
#pragma unroll
      for (int mt = 0; mt < 4; ++mt) acc[mt][nt] = mfma16(a[mt], bf, acc[mt][nt]);
    }
  }
#pragma unroll
  for (int mt = 0; mt < 4; ++mt)
#pragma unroll
    for (int nt = 0; nt < 4; ++nt) {
      int row0 = m0 + wm * 64 + mt * 16 + quad * 4;
      int col = n0 + wn * 64 + nt * 16 + ln;
      int sel = col >> 8, c = col & 255;
      u16x4 vv;
#pragma unroll
      for (int jj = 0; jj < 4; ++jj) vv[jj] = bf16rne(acc[mt][nt][jj]);
      if (sel == 2) {
        int b = row0 >> 12, s = row0 & 4095;
        *(u16x4*)(Vt + (size_t)b * 1048576 + (size_t)c * 4096 + s) = vv;
      } else {
        u16* dst = (sel == 0) ? Qb : Kb;
#pragma unroll
        for (int jj = 0; jj < 4; ++jj) dst[(size_t)(row0 + jj) * 256 + c] = vv[jj];
      }
    }
}

// ---------------- lambda scalar ----------------
__global__ void lam_kernel(const float* __restrict__ lq1, const float* __restrict__ lq2,
                           const float* __restrict__ lk1, const float* __restrict__ lk2,
                           float* __restrict__ lamp) {
  int t = threadIdx.x;  // 64 threads
  float d1 = lq1[t] * lk1[t] + lq1[t + 64] * lk1[t + 64];
  float d2 = lq2[t] * lk2[t] + lq2[t + 64] * lk2[t + 64];
#pragma unroll
  for (int off = 32; off; off >>= 1) {
    d1 += __shfl_xor(d1, off);
    d2 += __shfl_xor(d2, off);
  }
  if (t == 0) *lamp = expf(d1) + expf(d2) + (0.8f - 0.6f * expf(-3.6f));
}

// ------- fused flash attention: S^T=K.Q^T in regs, shuffle->PV, direct out -------
// 512 blocks (xcd-pinned batch), 4 waves = (map m, key-sub kt). Block owns 32 q
// rows for BOTH maps over ALL 4096 keys; epilogue reduces kt-pairs, normalizes,
// applies lam, writes final out. No partial buffers, no combine kernel.
__global__ __launch_bounds__(256, 2) void attn_kernel(const u16* __restrict__ Qb,
                                                      const u16* __restrict__ Kb,
                                                      const u16* __restrict__ Vt,
                                                      const float* __restrict__ lamp,
                                                      float* __restrict__ out) {
  const int bid = blockIdx.x;
  const int xcd = bid & 7;
  const int b = xcd >> 1;
  const int qt = ((bid >> 3) << 1) + (xcd & 1);  // 0..127, q rows qt*32..+32
  const int tid = threadIdx.x, lane = tid & 63, w = tid >> 6;
  const int l5 = lane & 31, lh = lane >> 5;
  const int m = w & 1, kt = w >> 1;

  __shared__ __align__(16) char smem[68096];
  u16* Ks = (u16*)smem;              // [64 keys][256 d], chunk-swizzled (32KB)
  u16* Vs = (u16*)(smem + 32768);    // [256 vcol][64 keys], chunk-swizzled (32KB)
  float* buf0 = (float*)smem;            // epilogue: map0 O^T [256][33]
  float* buf1 = (float*)(smem + 33792);  // epilogue: map1 O^T [256][33]
  float* ls = (float*)(smem + 67584);    // l partials [m*2+kt][32]

  // Q^T B-frags: B[k=d][n=q]: lane q = l5, d = s*16 + lh*8 + j
  s16x8 bq[8];
  {
    const u16* qp = Qb + ((size_t)(b * 4096 + qt * 32 + l5)) * 256 + m * 128 + lh * 8;
#pragma unroll
    for (int s = 0; s < 8; ++s) bq[s] = *(const s16x8*)(qp + s * 16);
  }

  f32x16 O[8];
#pragma unroll
  for (int ct = 0; ct < 8; ++ct)
#pragma unroll
    for (int r = 0; r < 16; ++r) O[ct][r] = 0.f;
  float l_run = 0.f;

  const u16* Kg0 = Kb + ((size_t)b * 4096) * 256;
  const u16* Vg0 = Vt + (size_t)b * 1048576;

  for (int kb = 0; kb < 4096; kb += 64) {
    __syncthreads();  // prev iter's Ks/Vs reads complete
    // stage K[64][256] (32KB)
#pragma unroll
    for (int i = 0; i < 8; ++i) {
      int p = tid + i * 256;
      int row = p >> 5, c = p & 31;
      int cg = (c & 16) | ((c ^ row) & 15);
      gl_lds16(Kg0 + (size_t)(kb + row) * 256 + cg * 8, Ks + (size_t)(p - lane) * 8);
    }
    // stage V^T[256][64] (32KB)
#pragma unroll
    for (int i = 0; i < 8; ++i) {
      int p = tid + i * 256;
      int row = p >> 3, c = p & 7;
      int cg = c ^ (row & 7);
      gl_lds16(Vg0 + (size_t)row * 4096 + kb + cg * 8, Vs + (size_t)(p - lane) * 8);
    }
    __syncthreads();  // staging complete

    // S^T[32 keys][32 q] = K . Q^T for (map m, keys kt*32..+32); two chains
    f32x16 Sa, Sb;
#pragma unroll
    for (int r = 0; r < 16; ++r) { Sa[r] = 0.f; Sb[r] = 0.f; }
#pragma unroll
    for (int s = 0; s < 8; s += 2) {
      int row = kt * 32 + l5;
      int c0 = m * 16 + s * 2 + lh;
      int c1 = m * 16 + (s + 1) * 2 + lh;
      s16x8 a0 = *(const s16x8*)(Ks + row * 256 + (((c0 & 16) | ((c0 ^ row) & 15))) * 8);
      s16x8 a1 = *(const s16x8*)(Ks + row * 256 + (((c1 & 16) | ((c1 ^ row) & 15))) * 8);
      Sa = mfma32(a0, bq[s], Sa);
      Sb = mfma32(a1, bq[s + 1], Sb);
    }

    // p = exp2(s); accumulate l; pack to dwords
    uint32_t P[8];
#pragma unroll
    for (int d = 0; d < 8; ++d) {
      float p0 = exp2f(Sa[2 * d] + Sb[2 * d]);
      float p1 = exp2f(Sa[2 * d + 1] + Sb[2 * d + 1]);
      l_run += p0 + p1;
      P[d] = (uint32_t)bf16rne(p0) | ((uint32_t)bf16rne(p1) << 16);
    }
    uint32_t X[8];
#pragma unroll
    for (int d = 0; d < 8; ++d) X[d] = (uint32_t)__shfl_xor((int)P[d], 32);

    // PV: O^T[256 vcol][32 q] += V^T . P^T over this wave's 32 keys (2 k-steps)
#pragma unroll
    for (int ks = 0; ks < 2; ++ks) {
      u32x4 fd;
      fd[0] = lh ? X[ks * 4 + 2] : P[ks * 4 + 0];
      fd[1] = lh ? X[ks * 4 + 3] : P[ks * 4 + 1];
      fd[2] = lh ? P[ks * 4 + 2] : X[ks * 4 + 0];
      fd[3] = lh ? P[ks * 4 + 3] : X[ks * 4 + 1];
      s16x8 pf = __builtin_bit_cast(s16x8, fd);
      int c = (kt * 32 + ks * 16) / 8 + lh;  // key-chunk within the 64 staged
#pragma unroll
      for (int ct = 0; ct < 8; ++ct) {
        int row = ct * 32 + l5;
        s16x8 vf = *(const s16x8*)(Vs + row * 64 + ((c ^ (row & 7)) * 8));
        O[ct] = mfma32(vf, pf, O[ct]);
      }
    }
  }

  // ---------------- epilogue ----------------
  float lam = *lamp;
  l_run += __shfl_xor(l_run, 32);  // fold lh (partner holds other 16 keys)
  __syncthreads();                 // B1: loop reads done; smem becomes buf0/buf1/ls
  if (lane < 32) ls[(m * 2 + kt) * 32 + l5] = l_run;
  float* bufm = m ? buf1 : buf0;
  if (kt == 1) {
#pragma unroll
    for (int ct = 0; ct < 8; ++ct)
#pragma unroll
      for (int r = 0; r < 16; ++r) {
        int vcol = ct * 32 + (r & 3) + 8 * (r >> 2) + 4 * lh;
        bufm[vcol * 33 + l5] = O[ct][r];
      }
  }
  __syncthreads();  // B2
  if (kt == 0) {
    float linv = 1.f / (ls[(m * 2) * 32 + l5] + ls[(m * 2 + 1) * 32 + l5]);
#pragma unroll
    for (int ct = 0; ct < 8; ++ct)
#pragma unroll
      for (int r = 0; r < 16; ++r) {
        int vcol = ct * 32 + (r & 3) + 8 * (r >> 2) + 4 * lh;
        bufm[vcol * 33 + l5] = (O[ct][r] + bufm[vcol * 33 + l5]) * linv;
      }
  }
  __syncthreads();  // B3
  // cooperative write: out[q][col], coalesced 256 threads = 256 cols
  float* og = out + ((size_t)(b * 4096 + qt * 32)) * 256;
#pragma unroll
  for (int j2 = 0; j2 < 32; ++j2) {
    float v = buf0[tid * 33 + j2] - lam * buf1[tid * 33 + j2];
    og[(size_t)j2 * 256 + tid] = v;
  }
}

extern "C" void kernel_launch(void* const* d_in, const int* in_sizes, int n_in,
                              void* d_out, int out_size, void* d_ws, size_t ws_size,
                              hipStream_t stream) {
  (void)in_sizes; (void)n_in; (void)out_size; (void)ws_size;
  const float* x   = (const float*)d_in[0];
  const float* WQ  = (const float*)d_in[1];
  const float* WK  = (const float*)d_in[2];
  const float* WV  = (const float*)d_in[3];
  const float* lq1 = (const float*)d_in[4];
  const float* lq2 = (const float*)d_in[5];
  const float* lk1 = (const float*)d_in[6];
  const float* lk2 = (const float*)d_in[7];
  float* out = (float*)d_out;

  char* ws = (char*)d_ws;
  u16* xb = (u16*)ws;   ws += (size_t)16384 * 2048 * 2;
  u16* Wt = (u16*)ws;   ws += (size_t)768 * 2048 * 2;
  u16* Qb = (u16*)ws;   ws += (size_t)16384 * 256 * 2;
  u16* Kb = (u16*)ws;   ws += (size_t)16384 * 256 * 2;
  u16* Vt = (u16*)ws;   ws += (size_t)16384 * 256 * 2;  // [b][col 256][s 4096]
  float* lamp = (float*)ws;

  const float qscale = 0.0883883476f * 1.44269504f;  // HEAD_DIM^-0.5 * log2(e)

  hipLaunchKernelGGL(cast_x_kernel, dim3(16384), dim3(256), 0, stream, x, xb);
  hipLaunchKernelGGL(cast_w_kernel, dim3(6144), dim3(256), 0, stream, WQ, WK, WV, Wt, qscale);
  hipLaunchKernelGGL(proj_gemm, dim3(768), dim3(256), 0, stream, xb, Wt, Qb, Kb, Vt);
  hipLaunchKernelGGL(lam_kernel, dim3(1), dim3(64), 0, stream, lq1, lq2, lk1, lk2, lamp);
  hipLaunchKernelGGL(attn_kernel, dim3(512), dim3(256), 0, stream, Qb, Kb, Vt, lamp, out);
}